// Round 11
// baseline (1729.717 us; speedup 1.0000x reference)
//
#include <hip/hip_runtime.h>

typedef unsigned short u16;
typedef unsigned int u32;

__device__ __forceinline__ float bf2f(u16 u){ union{u32 i; float f;} v; v.i=((u32)u)<<16; return v.f; }
__device__ __forceinline__ float bflo(u32 p){ union{u32 i; float f;} v; v.i=p<<16; return v.f; }
__device__ __forceinline__ float bfhi(u32 p){ union{u32 i; float f;} v; v.i=p&0xffff0000u; return v.f; }
__device__ __forceinline__ u16 f2bf(float x){ union{float f; u32 i;} v; v.f=x; u32 b=v.i;
  return (u16)((b + 0x7fffu + ((b>>16)&1u))>>16); }

#define HEADS 4
#define HHID 256   // HEADS*HID
#define NT 16      // nodes per block in k_xlr

// ---- fill d_out with a float value (diagnostic only) ----
__global__ void TopoAggregator_33217277067466_kernel(float* __restrict__ out, int n, float val){
  for(int i = blockIdx.x*blockDim.x + threadIdx.x; i < n; i += gridDim.x*blockDim.x)
    out[i] = val;
}

// ---- post-hoc invariant marker: touches d_out ONLY on failure ----
// codes: 400 CSR broken, 500 h all-zero
__global__ void k_marker(const int* __restrict__ rowstart, const float* __restrict__ h,
                         float* __restrict__ out, int N, int Et){
  if(threadIdx.x!=0 || blockIdx.x!=0) return;
  float M = 0.f;
  if(rowstart[N] != Et) M = 400.f;
  else {
    int allz = 1;
    for(int i=0;i<128;i++) if(h[i]!=0.f){ allz=0; break; }
    if(allz) M = 500.f;
  }
  if(M != 0.f) out[0] = M;
}

// ---- zero counts[N] and relmean[16] ----
__global__ void k_zero(int* __restrict__ counts, float* __restrict__ relmean, int N){
  int i = blockIdx.x*blockDim.x + threadIdx.x;
  if(i < N) counts[i] = 0;
  if(i < 16) relmean[i] = 0.f;
}

// ---- relation mean over E rows of 16 (f32) ----
__global__ void k_relmean(const float* __restrict__ rel, float* __restrict__ relmean, int E){
  __shared__ float red[256][16];
  float s[16];
#pragma unroll
  for(int j=0;j<16;j++) s[j]=0.f;
  for(int r = blockIdx.x*blockDim.x + threadIdx.x; r < E; r += gridDim.x*blockDim.x){
    const float4* p = (const float4*)(rel + (size_t)r*16);
    float4 a=p[0], b=p[1], c=p[2], d=p[3];
    s[0]+=a.x; s[1]+=a.y; s[2]+=a.z; s[3]+=a.w;
    s[4]+=b.x; s[5]+=b.y; s[6]+=b.z; s[7]+=b.w;
    s[8]+=c.x; s[9]+=c.y; s[10]+=c.z; s[11]+=c.w;
    s[12]+=d.x; s[13]+=d.y; s[14]+=d.z; s[15]+=d.w;
  }
  int tid = threadIdx.x;
#pragma unroll
  for(int j=0;j<16;j++) red[tid][j]=s[j];
  __syncthreads();
  for(int off=128; off>0; off>>=1){
    if(tid<off){
#pragma unroll
      for(int j=0;j<16;j++) red[tid][j]+=red[tid+off][j];
    }
    __syncthreads();
  }
  if(tid<16) atomicAdd(relmean+tid, red[0][tid]*(1.0f/(float)E));
}

// ---- CSR build ----
__global__ void k_count(const int* __restrict__ edges, int* __restrict__ counts, int E, int N){
  int Et = E + N;
  int e = blockIdx.x*blockDim.x + threadIdx.x;
  if(e>=Et) return;
  int d = (e<E) ? edges[E+e] : (e-E);
  if(d<0) d=0; if(d>=N) d=N-1;
  atomicAdd(counts+d, 1);
}

__global__ void k_scan(const int* __restrict__ counts, int* __restrict__ rowstart,
                       int* __restrict__ cursor, int N){
  __shared__ int part[1024];
  int tid = threadIdx.x;
  int chunk = (N + 1023) >> 10;
  int lo = tid*chunk, hi = lo+chunk; if(hi>N) hi=N; if(lo>N) lo=N;
  int s=0;
  for(int i=lo;i<hi;i++) s += counts[i];
  part[tid]=s;
  __syncthreads();
  for(int off=1; off<1024; off<<=1){
    int v = (tid>=off) ? part[tid-off] : 0;
    __syncthreads();
    part[tid] += v;
    __syncthreads();
  }
  int run = (tid==0) ? 0 : part[tid-1];
  for(int i=lo;i<hi;i++){ rowstart[i]=run; cursor[i]=run; run += counts[i]; }
  if(tid==1023) rowstart[N] = part[1023];
}

__global__ void k_scatter(const int* __restrict__ edges, int* __restrict__ cursor,
                          int* __restrict__ adj_src, int* __restrict__ adj_eid, int E, int N){
  int Et = E + N;
  int e = blockIdx.x*blockDim.x + threadIdx.x;
  if(e>=Et) return;
  int s, d;
  if(e<E){ s=edges[e]; d=edges[E+e]; } else { s=e-E; d=s; }
  if(d<0) d=0; if(d>=N) d=N-1;
  int pos = atomicAdd(cursor+d, 1);
  adj_src[pos]=s; adj_eid[pos]=e;
}

// ---- embedding + input projection: h[N][64] (f32) ----
__global__ void k_embed(const float* __restrict__ nodes,
                        const float* __restrict__ time_emb, const float* __restrict__ type_emb,
                        const float* __restrict__ biway_emb, const float* __restrict__ islink_emb,
                        const float* __restrict__ projw, const float* __restrict__ projb,
                        float* __restrict__ h, int N){
  __shared__ float W[64][65];
  __shared__ float h0[4][64];
  int tid = threadIdx.x;
  for(int i=tid; i<64*64; i+=256) W[i>>6][i&63] = projw[i];
  __syncthreads();
  int wave = tid>>6, lane = tid&63;
  int node = blockIdx.x*4 + wave;
  if(node<N){
    const float* nr = nodes + (size_t)node*20;
    float v; int c = lane;
    if(c<16){
      int t=(int)nr[0]; t = t<0?0:(t>287?287:t);
      v = time_emb[t*16+c];
    } else if(c<32){
      int ty=(int)nr[1]; ty = ty<0?0:(ty>15?15:ty);
      v = type_emb[ty*16+(c-16)];
    } else if(c<40){
      int bw=(int)nr[2]; bw = bw<0?0:(bw>1?1:bw);
      v = biway_emb[bw*8+(c-32)];
    } else if(c<48){
      int il=(int)nr[3]; il = il<0?0:(il>1?1:il);
      v = islink_emb[il*8+(c-40)];
    } else {
      v = nr[4 + (c-48)];
    }
    h0[wave][lane]=v;
  }
  __syncthreads();
  if(node<N){
    float acc = projb[lane];
#pragma unroll
    for(int k=0;k<64;k++) acc += W[lane][k]*h0[wave][k];
    h[(size_t)node*64+lane]=acc;
  }
}

// ---- xl/xr = h @ {wl,wr}.T + {bl,br}, stored bf16. 16 nodes/block ----
__global__ void k_xlr(const float* __restrict__ h,
                      const float* __restrict__ wl, const float* __restrict__ bl,
                      const float* __restrict__ wr, const float* __restrict__ br,
                      u16* __restrict__ xl, u16* __restrict__ xr, int N){
  __shared__ float hs[NT*64];
  int tid = threadIdx.x;
  int base = blockIdx.x*NT;
  int nvalid = N - base; if(nvalid > NT) nvalid = NT;
  if(nvalid == NT){
    *(float4*)(hs + tid*4) = *(const float4*)(h + (size_t)base*64 + tid*4);
  } else {
    for(int i=tid; i<NT*64; i+=256) hs[i] = (i < nvalid*64) ? h[(size_t)base*64+i] : 0.f;
  }
  __syncthreads();
  int o = tid;   // output channel 0..255
  const float4* wl4 = (const float4*)(wl + (size_t)o*64);
  const float4* wr4 = (const float4*)(wr + (size_t)o*64);
  float blv = bl[o], brv = br[o];
  float accl[NT], accr[NT];
#pragma unroll
  for(int n=0;n<NT;n++){ accl[n]=blv; accr[n]=brv; }
  for(int kk=0; kk<16; kk++){
    float4 a = wl4[kk];
    float4 b = wr4[kk];
#pragma unroll
    for(int n=0;n<NT;n++){
      float4 hv = *(const float4*)(hs + n*64 + kk*4);
      accl[n] += a.x*hv.x + a.y*hv.y + a.z*hv.z + a.w*hv.w;
      accr[n] += b.x*hv.x + b.y*hv.y + b.z*hv.z + b.w*hv.w;
    }
  }
  for(int n=0;n<nvalid;n++){
    xl[(size_t)(base+n)*HHID + o] = f2bf(accl[n]);
    xr[(size_t)(base+n)*HHID + o] = f2bf(accr[n]);
  }
}

// ---- fused per-node: edge logits + online softmax + aggregation + residual ----
// r9 structure; eid/src made wave-uniform via readfirstlane so the rel row
// prefetch lands in SGPRs (s_load) — 1-deep data pipeline at ~zero VGPR cost.
__global__ void __launch_bounds__(256, 4)
k_fused(const int* __restrict__ rowstart, const int* __restrict__ adj_src,
        const int* __restrict__ adj_eid,
        const float* __restrict__ relation, const float* __restrict__ relmean,
        const float* __restrict__ we, const float* __restrict__ att,
        const u16* __restrict__ xl, const u16* __restrict__ xr,
        const float* __restrict__ gat_b,
        float* __restrict__ h, int N, int E, float* __restrict__ outp){
  const int lane = threadIdx.x & 63;
  const int sub = lane & 15;
  const int wid = (blockIdx.x*blockDim.x + threadIdx.x) >> 6;
  const int nw  = (gridDim.x*blockDim.x) >> 6;

  // per-wave constants: this lane's 4 we-rows (64 floats), att quad
  float wreg[64];
  {
    const float4* wp = (const float4*)(we + (size_t)lane*64);
#pragma unroll
    for(int i=0;i<16;i++){
      float4 t = wp[i];
      wreg[i*4+0]=t.x; wreg[i*4+1]=t.y; wreg[i*4+2]=t.z; wreg[i*4+3]=t.w;
    }
  }
  const float4 at4 = *(const float4*)(att + lane*4);

  for(int node = wid; node < N; node += nw){
    const int lo = rowstart[node], hi = rowstart[node+1];
    uint2 pb = *(const uint2*)(xr + (size_t)node*HHID + lane*4);
    float bv0=bflo(pb.x), bv1=bfhi(pb.x), bv2=bflo(pb.y), bv3=bfhi(pb.y);

    float m = -1e30f, den = 0.f;
    float a0=0.f, a1=0.f, a2=0.f, a3=0.f;

    // prologue: uniform idx for lo, lo+1; data for lo
    int eidB=0, svB=0;
    float4 rA0=make_float4(0,0,0,0), rA1=rA0, rA2=rA0, rA3=rA0;
    uint2 paA = make_uint2(0u,0u);
    float avA0=0.f, avA1=0.f, avA2=0.f, avA3=0.f;
    if(lo < hi){
      int eu = __builtin_amdgcn_readfirstlane(adj_eid[lo]);
      int su = __builtin_amdgcn_readfirstlane(adj_src[lo]);
      su = su<0?0:(su>=N?N-1:su);
      const float4* rp = (eu < E) ? (const float4*)(relation + (size_t)eu*16)
                                  : (const float4*)relmean;
      rA0=rp[0]; rA1=rp[1]; rA2=rp[2]; rA3=rp[3];
      paA = *(const uint2*)(xl + (size_t)su*HHID + lane*4);
    }
    if(lo+1 < hi){
      eidB = __builtin_amdgcn_readfirstlane(adj_eid[lo+1]);
      svB  = __builtin_amdgcn_readfirstlane(adj_src[lo+1]);
    }

    for(int p=lo; p<hi; p++){
      // stage 1: data loads for p+1 (uniform rel row -> SGPRs; pa gather)
      float4 rB0=make_float4(0,0,0,0), rB1=rB0, rB2=rB0, rB3=rB0;
      uint2 paB = make_uint2(0u,0u);
      if(p+1 < hi){
        int su = svB; su = su<0?0:(su>=N?N-1:su);
        const float4* rp = (eidB < E) ? (const float4*)(relation + (size_t)eidB*16)
                                      : (const float4*)relmean;
        rB0=rp[0]; rB1=rp[1]; rB2=rp[2]; rB3=rp[3];
        paB = *(const uint2*)(xl + (size_t)su*HHID + lane*4);
      }
      // stage 2: uniform idx loads for p+2
      int eidC=0, svC=0;
      if(p+2 < hi){
        eidC = __builtin_amdgcn_readfirstlane(adj_eid[p+2]);
        svC  = __builtin_amdgcn_readfirstlane(adj_src[p+2]);
      }

      // stage 3: compute edge p on resident rA*/paA
      float av0=bflo(paA.x), av1=bfhi(paA.x), av2=bflo(paA.y), av3=bfhi(paA.y);
      float rc[16];
      rc[0]=rA0.x; rc[1]=rA0.y; rc[2]=rA0.z; rc[3]=rA0.w;
      rc[4]=rA1.x; rc[5]=rA1.y; rc[6]=rA1.z; rc[7]=rA1.w;
      rc[8]=rA2.x; rc[9]=rA2.y; rc[10]=rA2.z; rc[11]=rA2.w;
      rc[12]=rA3.x; rc[13]=rA3.y; rc[14]=rA3.z; rc[15]=rA3.w;
      float c = 0.f;
#pragma unroll
      for(int j=0;j<4;j++){
        float ep = 0.f;
#pragma unroll
        for(int k=0;k<16;k++) ep += rc[k]*wreg[j*16+k];
        float avj = (j==0)?av0:(j==1)?av1:(j==2)?av2:av3;
        float bvj = (j==0)?bv0:(j==1)?bv1:(j==2)?bv2:bv3;
        float mm = avj + bvj + ep;
        mm = (mm>0.f) ? mm : 0.2f*mm;
        float atj = (j==0)?at4.x:(j==1)?at4.y:(j==2)?at4.z:at4.w;
        c += mm*atj;
      }
      c += __shfl_xor(c, 1);
      c += __shfl_xor(c, 2);
      c += __shfl_xor(c, 4);
      c += __shfl_xor(c, 8);

      // online softmax update (r9 form)
      if(c > m){
        float sc = __expf(m - c);
        den *= sc; a0 *= sc; a1 *= sc; a2 *= sc; a3 *= sc;
        m = c;
      }
      float wgt = __expf(c - m);
      den += wgt;
      a0 += wgt*av0; a1 += wgt*av1; a2 += wgt*av2; a3 += wgt*av3;

      // rotate pipeline
      rA0=rB0; rA1=rB1; rA2=rB2; rA3=rB3;
      paA = paB;
      eidB = eidC; svB = svC;
    }

    float inv = 1.0f/den;   // den>0: every node has a self-loop
    float v0=a0*inv, v1=a1*inv, v2=a2*inv, v3=a3*inv;
    v0 += __shfl_xor(v0,16); v0 += __shfl_xor(v0,32);
    v1 += __shfl_xor(v1,16); v1 += __shfl_xor(v1,32);
    v2 += __shfl_xor(v2,16); v2 += __shfl_xor(v2,32);
    v3 += __shfl_xor(v3,16); v3 += __shfl_xor(v3,32);
    if(lane < 16){
      int cb = sub*4;
      float4 hv = *(const float4*)(h + (size_t)node*64 + cb);
      const float4 gb = *(const float4*)(gat_b + cb);
      float o0 = fmaxf(0.25f*v0 + gb.x + hv.x, 0.f);
      float o1 = fmaxf(0.25f*v1 + gb.y + hv.y, 0.f);
      float o2 = fmaxf(0.25f*v2 + gb.z + hv.z, 0.f);
      float o3 = fmaxf(0.25f*v3 + gb.w + hv.w, 0.f);
      *(float4*)(h + (size_t)node*64 + cb) = make_float4(o0,o1,o2,o3);
      if(outp) *(float4*)(outp + (size_t)node*64 + cb) = make_float4(o0,o1,o2,o3);
    }
  }
}

extern "C" void kernel_launch(void* const* d_in, const int* in_sizes, int n_in,
                              void* d_out, int out_size, void* d_ws, size_t ws_size,
                              hipStream_t stream) {
  const float* nodes     = (const float*)d_in[0];
  const int*   edges     = (const int*)d_in[1];
  const float* relation  = (const float*)d_in[2];
  const float* time_emb  = (const float*)d_in[3];
  const float* type_emb  = (const float*)d_in[4];
  const float* biway_emb = (const float*)d_in[5];
  const float* islink_emb= (const float*)d_in[6];
  const float* proj_w    = (const float*)d_in[7];
  const float* proj_b    = (const float*)d_in[8];
  const float* lin_l_w   = (const float*)d_in[9];
  const float* lin_l_b   = (const float*)d_in[10];
  const float* lin_r_w   = (const float*)d_in[11];
  const float* lin_r_b   = (const float*)d_in[12];
  const float* lin_e_w   = (const float*)d_in[13];
  const float* att       = (const float*)d_in[14];
  const float* gat_b     = (const float*)d_in[15];

  const int N  = in_sizes[0] / 20;
  const int E  = in_sizes[1] / 2;
  const int Et = E + N;

  size_t off = 0;
  auto alloc = [&](size_t bytes)->size_t {
    size_t p = off;
    off += ((bytes + 255) / 256) * 256;
    return p;
  };
  size_t o_h        = alloc((size_t)N*64*4);        // f32
  size_t o_xl       = alloc((size_t)N*HHID*2);      // bf16
  size_t o_xr       = alloc((size_t)N*HHID*2);      // bf16
  size_t o_relmean  = alloc(64*4);
  size_t o_counts   = alloc((size_t)N*4);
  size_t o_rowstart = alloc((size_t)(N+1)*4);
  size_t o_cursor   = alloc((size_t)(N+1)*4);
  size_t o_adjsrc   = alloc((size_t)Et*4);
  size_t o_adjeid   = alloc((size_t)Et*4);

  if (off > ws_size) {
    TopoAggregator_33217277067466_kernel<<<2048, 256, 0, stream>>>(
        (float*)d_out, out_size, 100.0f);   // marker ~100: ws too small
    return;
  }

  char* w = (char*)d_ws;
  float* h        = (float*)(w + o_h);
  u16*   xl       = (u16*)(w + o_xl);
  u16*   xr       = (u16*)(w + o_xr);
  float* relmean  = (float*)(w + o_relmean);
  int*   counts   = (int*)(w + o_counts);
  int*   rowstart = (int*)(w + o_rowstart);
  int*   cursor   = (int*)(w + o_cursor);
  int*   adj_src  = (int*)(w + o_adjsrc);
  int*   adj_eid  = (int*)(w + o_adjeid);

  k_zero<<<(N+255)/256, 256, 0, stream>>>(counts, relmean, N);
  k_relmean<<<64, 256, 0, stream>>>(relation, relmean, E);
  k_count<<<(Et+255)/256, 256, 0, stream>>>(edges, counts, E, N);
  k_scan<<<1, 1024, 0, stream>>>(counts, rowstart, cursor, N);
  k_scatter<<<(Et+255)/256, 256, 0, stream>>>(edges, cursor, adj_src, adj_eid, E, N);

  k_embed<<<(N+3)/4, 256, 0, stream>>>(nodes, time_emb, type_emb, biway_emb, islink_emb,
                                       proj_w, proj_b, h, N);

  for(int l=0; l<2; l++){
    k_xlr<<<(N+NT-1)/NT, 256, 0, stream>>>(h,
        lin_l_w + (size_t)l*HHID*64, lin_l_b + (size_t)l*HHID,
        lin_r_w + (size_t)l*HHID*64, lin_r_b + (size_t)l*HHID,
        xl, xr, N);
    k_fused<<<4096, 256, 0, stream>>>(rowstart, adj_src, adj_eid,
        relation, relmean,
        lin_e_w + (size_t)l*HHID*16, att + (size_t)l*HEADS*64,
        xl, xr, gat_b + (size_t)l*64,
        h, N, E,
        (l==1) ? (float*)d_out : (float*)nullptr);
  }
  k_marker<<<1, 64, 0, stream>>>(rowstart, h, (float*)d_out, N, Et);
}

// Round 12
// 1211.581 us; speedup vs baseline: 1.4277x; 1.4277x over previous
//
#include <hip/hip_runtime.h>

typedef unsigned short u16;
typedef unsigned int u32;

__device__ __forceinline__ float bf2f(u16 u){ union{u32 i; float f;} v; v.i=((u32)u)<<16; return v.f; }
__device__ __forceinline__ float bflo(u32 p){ union{u32 i; float f;} v; v.i=p<<16; return v.f; }
__device__ __forceinline__ float bfhi(u32 p){ union{u32 i; float f;} v; v.i=p&0xffff0000u; return v.f; }
__device__ __forceinline__ u16 f2bf(float x){ union{float f; u32 i;} v; v.f=x; u32 b=v.i;
  return (u16)((b + 0x7fffu + ((b>>16)&1u))>>16); }

#define HEADS 4
#define HHID 256   // HEADS*HID
#define NT 16      // nodes per block in k_xlr

// ---- fill d_out with a float value (diagnostic only) ----
__global__ void TopoAggregator_33217277067466_kernel(float* __restrict__ out, int n, float val){
  for(int i = blockIdx.x*blockDim.x + threadIdx.x; i < n; i += gridDim.x*blockDim.x)
    out[i] = val;
}

// ---- post-hoc invariant marker: touches d_out ONLY on failure ----
// codes: 400 CSR broken, 500 h all-zero
__global__ void k_marker(const int* __restrict__ rowstart, const float* __restrict__ h,
                         float* __restrict__ out, int N, int Et){
  if(threadIdx.x!=0 || blockIdx.x!=0) return;
  float M = 0.f;
  if(rowstart[N] != Et) M = 400.f;
  else {
    int allz = 1;
    for(int i=0;i<128;i++) if(h[i]!=0.f){ allz=0; break; }
    if(allz) M = 500.f;
  }
  if(M != 0.f) out[0] = M;
}

// ---- zero counts[N] and relmean[16] ----
__global__ void k_zero(int* __restrict__ counts, float* __restrict__ relmean, int N){
  int i = blockIdx.x*blockDim.x + threadIdx.x;
  if(i < N) counts[i] = 0;
  if(i < 16) relmean[i] = 0.f;
}

// ---- relation mean over E rows of 16 (f32) ----
__global__ void k_relmean(const float* __restrict__ rel, float* __restrict__ relmean, int E){
  __shared__ float red[256][16];
  float s[16];
#pragma unroll
  for(int j=0;j<16;j++) s[j]=0.f;
  for(int r = blockIdx.x*blockDim.x + threadIdx.x; r < E; r += gridDim.x*blockDim.x){
    const float4* p = (const float4*)(rel + (size_t)r*16);
    float4 a=p[0], b=p[1], c=p[2], d=p[3];
    s[0]+=a.x; s[1]+=a.y; s[2]+=a.z; s[3]+=a.w;
    s[4]+=b.x; s[5]+=b.y; s[6]+=b.z; s[7]+=b.w;
    s[8]+=c.x; s[9]+=c.y; s[10]+=c.z; s[11]+=c.w;
    s[12]+=d.x; s[13]+=d.y; s[14]+=d.z; s[15]+=d.w;
  }
  int tid = threadIdx.x;
#pragma unroll
  for(int j=0;j<16;j++) red[tid][j]=s[j];
  __syncthreads();
  for(int off=128; off>0; off>>=1){
    if(tid<off){
#pragma unroll
      for(int j=0;j<16;j++) red[tid][j]+=red[tid+off][j];
    }
    __syncthreads();
  }
  if(tid<16) atomicAdd(relmean+tid, red[0][tid]*(1.0f/(float)E));
}

// ---- CSR build ----
__global__ void k_count(const int* __restrict__ edges, int* __restrict__ counts, int E, int N){
  int Et = E + N;
  int e = blockIdx.x*blockDim.x + threadIdx.x;
  if(e>=Et) return;
  int d = (e<E) ? edges[E+e] : (e-E);
  if(d<0) d=0; if(d>=N) d=N-1;
  atomicAdd(counts+d, 1);
}

__global__ void k_scan(const int* __restrict__ counts, int* __restrict__ rowstart,
                       int* __restrict__ cursor, int N){
  __shared__ int part[1024];
  int tid = threadIdx.x;
  int chunk = (N + 1023) >> 10;
  int lo = tid*chunk, hi = lo+chunk; if(hi>N) hi=N; if(lo>N) lo=N;
  int s=0;
  for(int i=lo;i<hi;i++) s += counts[i];
  part[tid]=s;
  __syncthreads();
  for(int off=1; off<1024; off<<=1){
    int v = (tid>=off) ? part[tid-off] : 0;
    __syncthreads();
    part[tid] += v;
    __syncthreads();
  }
  int run = (tid==0) ? 0 : part[tid-1];
  for(int i=lo;i<hi;i++){ rowstart[i]=run; cursor[i]=run; run += counts[i]; }
  if(tid==1023) rowstart[N] = part[1023];
}

__global__ void k_scatter(const int* __restrict__ edges, int* __restrict__ cursor,
                          int* __restrict__ adj_src, int* __restrict__ adj_eid, int E, int N){
  int Et = E + N;
  int e = blockIdx.x*blockDim.x + threadIdx.x;
  if(e>=Et) return;
  int s, d;
  if(e<E){ s=edges[e]; d=edges[E+e]; } else { s=e-E; d=s; }
  if(d<0) d=0; if(d>=N) d=N-1;
  int pos = atomicAdd(cursor+d, 1);
  adj_src[pos]=s; adj_eid[pos]=e;
}

// ---- embedding + input projection: h[N][64] (f32) ----
__global__ void k_embed(const float* __restrict__ nodes,
                        const float* __restrict__ time_emb, const float* __restrict__ type_emb,
                        const float* __restrict__ biway_emb, const float* __restrict__ islink_emb,
                        const float* __restrict__ projw, const float* __restrict__ projb,
                        float* __restrict__ h, int N){
  __shared__ float W[64][65];
  __shared__ float h0[4][64];
  int tid = threadIdx.x;
  for(int i=tid; i<64*64; i+=256) W[i>>6][i&63] = projw[i];
  __syncthreads();
  int wave = tid>>6, lane = tid&63;
  int node = blockIdx.x*4 + wave;
  if(node<N){
    const float* nr = nodes + (size_t)node*20;
    float v; int c = lane;
    if(c<16){
      int t=(int)nr[0]; t = t<0?0:(t>287?287:t);
      v = time_emb[t*16+c];
    } else if(c<32){
      int ty=(int)nr[1]; ty = ty<0?0:(ty>15?15:ty);
      v = type_emb[ty*16+(c-16)];
    } else if(c<40){
      int bw=(int)nr[2]; bw = bw<0?0:(bw>1?1:bw);
      v = biway_emb[bw*8+(c-32)];
    } else if(c<48){
      int il=(int)nr[3]; il = il<0?0:(il>1?1:il);
      v = islink_emb[il*8+(c-40)];
    } else {
      v = nr[4 + (c-48)];
    }
    h0[wave][lane]=v;
  }
  __syncthreads();
  if(node<N){
    float acc = projb[lane];
#pragma unroll
    for(int k=0;k<64;k++) acc += W[lane][k]*h0[wave][k];
    h[(size_t)node*64+lane]=acc;
  }
}

// ---- xl/xr = h @ {wl,wr}.T + {bl,br}, stored bf16. 16 nodes/block ----
__global__ void k_xlr(const float* __restrict__ h,
                      const float* __restrict__ wl, const float* __restrict__ bl,
                      const float* __restrict__ wr, const float* __restrict__ br,
                      u16* __restrict__ xl, u16* __restrict__ xr, int N){
  __shared__ float hs[NT*64];
  int tid = threadIdx.x;
  int base = blockIdx.x*NT;
  int nvalid = N - base; if(nvalid > NT) nvalid = NT;
  if(nvalid == NT){
    *(float4*)(hs + tid*4) = *(const float4*)(h + (size_t)base*64 + tid*4);
  } else {
    for(int i=tid; i<NT*64; i+=256) hs[i] = (i < nvalid*64) ? h[(size_t)base*64+i] : 0.f;
  }
  __syncthreads();
  int o = tid;   // output channel 0..255
  const float4* wl4 = (const float4*)(wl + (size_t)o*64);
  const float4* wr4 = (const float4*)(wr + (size_t)o*64);
  float blv = bl[o], brv = br[o];
  float accl[NT], accr[NT];
#pragma unroll
  for(int n=0;n<NT;n++){ accl[n]=blv; accr[n]=brv; }
  for(int kk=0; kk<16; kk++){
    float4 a = wl4[kk];
    float4 b = wr4[kk];
#pragma unroll
    for(int n=0;n<NT;n++){
      float4 hv = *(const float4*)(hs + n*64 + kk*4);
      accl[n] += a.x*hv.x + a.y*hv.y + a.z*hv.z + a.w*hv.w;
      accr[n] += b.x*hv.x + b.y*hv.y + b.z*hv.z + b.w*hv.w;
    }
  }
  for(int n=0;n<nvalid;n++){
    xl[(size_t)(base+n)*HHID + o] = f2bf(accl[n]);
    xr[(size_t)(base+n)*HHID + o] = f2bf(accr[n]);
  }
}

// ---- fused per-node: edge logits + online softmax + aggregation + residual ----
// r9 structure exactly; the only change is the hoisted we-rows are stored as
// packed bf16 pairs (32 VGPRs instead of 64) so the kernel fits the 64-VGPR
// budget without scratch spills.
__global__ void k_fused(const int* __restrict__ rowstart, const int* __restrict__ adj_src,
                        const int* __restrict__ adj_eid,
                        const float* __restrict__ relation, const float* __restrict__ relmean,
                        const float* __restrict__ we, const float* __restrict__ att,
                        const u16* __restrict__ xl, const u16* __restrict__ xr,
                        const float* __restrict__ gat_b,
                        float* __restrict__ h, int N, int E, float* __restrict__ outp){
  const int lane = threadIdx.x & 63;
  const int sub = lane & 15;
  const int wid = (blockIdx.x*blockDim.x + threadIdx.x) >> 6;
  const int nw  = (gridDim.x*blockDim.x) >> 6;

  // per-wave constants: this lane's 4 we-rows, packed bf16 (32 regs), att quad
  u32 wpk[32];
  {
    const float4* wp = (const float4*)(we + (size_t)lane*64);
#pragma unroll
    for(int i=0;i<16;i++){
      float4 t = wp[i];
      wpk[i*2+0] = ((u32)f2bf(t.y) << 16) | (u32)f2bf(t.x);
      wpk[i*2+1] = ((u32)f2bf(t.w) << 16) | (u32)f2bf(t.z);
    }
  }
  const float4 at4 = *(const float4*)(att + lane*4);

  for(int node = wid; node < N; node += nw){
    const int lo = rowstart[node], hi = rowstart[node+1];
    uint2 pb = *(const uint2*)(xr + (size_t)node*HHID + lane*4);
    float bv0=bflo(pb.x), bv1=bfhi(pb.x), bv2=bflo(pb.y), bv3=bfhi(pb.y);

    float m = -1e30f, den = 0.f;
    float a0=0.f, a1=0.f, a2=0.f, a3=0.f;

    // prefetch first neighbor's indices
    int eid0=0, sv0=0;
    if(lo < hi){ eid0 = adj_eid[lo]; sv0 = adj_src[lo]; }

    for(int p=lo; p<hi; p++){
      // prefetch next indices (breaks the idx->data chain)
      int eid1=0, sv1=0;
      if(p+1 < hi){ eid1 = adj_eid[p+1]; sv1 = adj_src[p+1]; }
      int sv = sv0; if(sv<0) sv=0; if(sv>=N) sv=N-1;

      // gather current data
      float rc[16];
      {
        const float4* rp = (eid0 < E) ? (const float4*)(relation + (size_t)eid0*16)
                                      : (const float4*)relmean;
        float4 q0=rp[0], q1=rp[1], q2=rp[2], q3=rp[3];
        rc[0]=q0.x; rc[1]=q0.y; rc[2]=q0.z; rc[3]=q0.w;
        rc[4]=q1.x; rc[5]=q1.y; rc[6]=q1.z; rc[7]=q1.w;
        rc[8]=q2.x; rc[9]=q2.y; rc[10]=q2.z; rc[11]=q2.w;
        rc[12]=q3.x; rc[13]=q3.y; rc[14]=q3.z; rc[15]=q3.w;
      }
      uint2 pa = *(const uint2*)(xl + (size_t)sv*HHID + lane*4);
      float av0=bflo(pa.x), av1=bfhi(pa.x), av2=bflo(pa.y), av3=bfhi(pa.y);

      // logit for this edge
      float c = 0.f;
#pragma unroll
      for(int j=0;j<4;j++){
        float ep = 0.f;
#pragma unroll
        for(int kk=0;kk<8;kk++){
          u32 w = wpk[j*8+kk];
          ep += rc[2*kk]*bflo(w) + rc[2*kk+1]*bfhi(w);
        }
        float avj = (j==0)?av0:(j==1)?av1:(j==2)?av2:av3;
        float bvj = (j==0)?bv0:(j==1)?bv1:(j==2)?bv2:bv3;
        float mm = avj + bvj + ep;
        mm = (mm>0.f) ? mm : 0.2f*mm;
        float atj = (j==0)?at4.x:(j==1)?at4.y:(j==2)?at4.z:at4.w;
        c += mm*atj;
      }
      c += __shfl_xor(c, 1);
      c += __shfl_xor(c, 2);
      c += __shfl_xor(c, 4);
      c += __shfl_xor(c, 8);

      // online softmax update (uniform within the 16-lane head group)
      if(c > m){
        float sc = __expf(m - c);
        den *= sc; a0 *= sc; a1 *= sc; a2 *= sc; a3 *= sc;
        m = c;
      }
      float wgt = __expf(c - m);
      den += wgt;
      a0 += wgt*av0; a1 += wgt*av1; a2 += wgt*av2; a3 += wgt*av3;

      eid0 = eid1; sv0 = sv1;
    }

    float inv = 1.0f/den;   // den>0: every node has a self-loop
    float v0=a0*inv, v1=a1*inv, v2=a2*inv, v3=a3*inv;
    v0 += __shfl_xor(v0,16); v0 += __shfl_xor(v0,32);
    v1 += __shfl_xor(v1,16); v1 += __shfl_xor(v1,32);
    v2 += __shfl_xor(v2,16); v2 += __shfl_xor(v2,32);
    v3 += __shfl_xor(v3,16); v3 += __shfl_xor(v3,32);
    if(lane < 16){
      int cb = sub*4;
      float4 hv = *(const float4*)(h + (size_t)node*64 + cb);
      const float4 gb = *(const float4*)(gat_b + cb);
      float o0 = fmaxf(0.25f*v0 + gb.x + hv.x, 0.f);
      float o1 = fmaxf(0.25f*v1 + gb.y + hv.y, 0.f);
      float o2 = fmaxf(0.25f*v2 + gb.z + hv.z, 0.f);
      float o3 = fmaxf(0.25f*v3 + gb.w + hv.w, 0.f);
      *(float4*)(h + (size_t)node*64 + cb) = make_float4(o0,o1,o2,o3);
      if(outp) *(float4*)(outp + (size_t)node*64 + cb) = make_float4(o0,o1,o2,o3);
    }
  }
}

extern "C" void kernel_launch(void* const* d_in, const int* in_sizes, int n_in,
                              void* d_out, int out_size, void* d_ws, size_t ws_size,
                              hipStream_t stream) {
  const float* nodes     = (const float*)d_in[0];
  const int*   edges     = (const int*)d_in[1];
  const float* relation  = (const float*)d_in[2];
  const float* time_emb  = (const float*)d_in[3];
  const float* type_emb  = (const float*)d_in[4];
  const float* biway_emb = (const float*)d_in[5];
  const float* islink_emb= (const float*)d_in[6];
  const float* proj_w    = (const float*)d_in[7];
  const float* proj_b    = (const float*)d_in[8];
  const float* lin_l_w   = (const float*)d_in[9];
  const float* lin_l_b   = (const float*)d_in[10];
  const float* lin_r_w   = (const float*)d_in[11];
  const float* lin_r_b   = (const float*)d_in[12];
  const float* lin_e_w   = (const float*)d_in[13];
  const float* att       = (const float*)d_in[14];
  const float* gat_b     = (const float*)d_in[15];

  const int N  = in_sizes[0] / 20;
  const int E  = in_sizes[1] / 2;
  const int Et = E + N;

  size_t off = 0;
  auto alloc = [&](size_t bytes)->size_t {
    size_t p = off;
    off += ((bytes + 255) / 256) * 256;
    return p;
  };
  size_t o_h        = alloc((size_t)N*64*4);        // f32
  size_t o_xl       = alloc((size_t)N*HHID*2);      // bf16
  size_t o_xr       = alloc((size_t)N*HHID*2);      // bf16
  size_t o_relmean  = alloc(64*4);
  size_t o_counts   = alloc((size_t)N*4);
  size_t o_rowstart = alloc((size_t)(N+1)*4);
  size_t o_cursor   = alloc((size_t)(N+1)*4);
  size_t o_adjsrc   = alloc((size_t)Et*4);
  size_t o_adjeid   = alloc((size_t)Et*4);

  if (off > ws_size) {
    TopoAggregator_33217277067466_kernel<<<2048, 256, 0, stream>>>(
        (float*)d_out, out_size, 100.0f);   // marker ~100: ws too small
    return;
  }

  char* w = (char*)d_ws;
  float* h        = (float*)(w + o_h);
  u16*   xl       = (u16*)(w + o_xl);
  u16*   xr       = (u16*)(w + o_xr);
  float* relmean  = (float*)(w + o_relmean);
  int*   counts   = (int*)(w + o_counts);
  int*   rowstart = (int*)(w + o_rowstart);
  int*   cursor   = (int*)(w + o_cursor);
  int*   adj_src  = (int*)(w + o_adjsrc);
  int*   adj_eid  = (int*)(w + o_adjeid);

  k_zero<<<(N+255)/256, 256, 0, stream>>>(counts, relmean, N);
  k_relmean<<<64, 256, 0, stream>>>(relation, relmean, E);
  k_count<<<(Et+255)/256, 256, 0, stream>>>(edges, counts, E, N);
  k_scan<<<1, 1024, 0, stream>>>(counts, rowstart, cursor, N);
  k_scatter<<<(Et+255)/256, 256, 0, stream>>>(edges, cursor, adj_src, adj_eid, E, N);

  k_embed<<<(N+3)/4, 256, 0, stream>>>(nodes, time_emb, type_emb, biway_emb, islink_emb,
                                       proj_w, proj_b, h, N);

  for(int l=0; l<2; l++){
    k_xlr<<<(N+NT-1)/NT, 256, 0, stream>>>(h,
        lin_l_w + (size_t)l*HHID*64, lin_l_b + (size_t)l*HHID,
        lin_r_w + (size_t)l*HHID*64, lin_r_b + (size_t)l*HHID,
        xl, xr, N);
    k_fused<<<4096, 256, 0, stream>>>(rowstart, adj_src, adj_eid,
        relation, relmean,
        lin_e_w + (size_t)l*HHID*16, att + (size_t)l*HEADS*64,
        xl, xr, gat_b + (size_t)l*64,
        h, N, E,
        (l==1) ? (float*)d_out : (float*)nullptr);
  }
  k_marker<<<1, 64, 0, stream>>>(rowstart, h, (float*)d_out, N, Et);
}

// Round 13
// 1083.404 us; speedup vs baseline: 1.5966x; 1.1183x over previous
//
#include <hip/hip_runtime.h>

typedef unsigned short u16;
typedef unsigned int u32;

__device__ __forceinline__ float bf2f(u16 u){ union{u32 i; float f;} v; v.i=((u32)u)<<16; return v.f; }
__device__ __forceinline__ float bflo(u32 p){ union{u32 i; float f;} v; v.i=p<<16; return v.f; }
__device__ __forceinline__ float bfhi(u32 p){ union{u32 i; float f;} v; v.i=p&0xffff0000u; return v.f; }
__device__ __forceinline__ u16 f2bf(float x){ union{float f; u32 i;} v; v.f=x; u32 b=v.i;
  return (u16)((b + 0x7fffu + ((b>>16)&1u))>>16); }
__device__ __forceinline__ u32 pk2(float a, float b){ return ((u32)f2bf(b)<<16) | (u32)f2bf(a); }

#define HEADS 4
#define HHID 256   // HEADS*HID
#define NT 16      // nodes per block in k_xlr

// ---- fill d_out with a float value (diagnostic only) ----
__global__ void TopoAggregator_33217277067466_kernel(float* __restrict__ out, int n, float val){
  for(int i = blockIdx.x*blockDim.x + threadIdx.x; i < n; i += gridDim.x*blockDim.x)
    out[i] = val;
}

// ---- post-hoc invariant marker: touches d_out ONLY on failure ----
// codes: 400 CSR broken, 500 h all-zero
__global__ void k_marker(const int* __restrict__ rowstart, const float* __restrict__ h,
                         float* __restrict__ out, int N, int E){
  if(threadIdx.x!=0 || blockIdx.x!=0) return;
  float M = 0.f;
  if(rowstart[N] != E) M = 400.f;
  else {
    int allz = 1;
    for(int i=0;i<128;i++) if(h[i]!=0.f){ allz=0; break; }
    if(allz) M = 500.f;
  }
  if(M != 0.f) out[0] = M;
}

// ---- zero counts[N] and relmean[16] ----
__global__ void k_zero(int* __restrict__ counts, float* __restrict__ relmean, int N){
  int i = blockIdx.x*blockDim.x + threadIdx.x;
  if(i < N) counts[i] = 0;
  if(i < 16) relmean[i] = 0.f;
}

// ---- relation mean over E rows of 16 (f32) ----
__global__ void k_relmean(const float* __restrict__ rel, float* __restrict__ relmean, int E){
  __shared__ float red[256][16];
  float s[16];
#pragma unroll
  for(int j=0;j<16;j++) s[j]=0.f;
  for(int r = blockIdx.x*blockDim.x + threadIdx.x; r < E; r += gridDim.x*blockDim.x){
    const float4* p = (const float4*)(rel + (size_t)r*16);
    float4 a=p[0], b=p[1], c=p[2], d=p[3];
    s[0]+=a.x; s[1]+=a.y; s[2]+=a.z; s[3]+=a.w;
    s[4]+=b.x; s[5]+=b.y; s[6]+=b.z; s[7]+=b.w;
    s[8]+=c.x; s[9]+=c.y; s[10]+=c.z; s[11]+=c.w;
    s[12]+=d.x; s[13]+=d.y; s[14]+=d.z; s[15]+=d.w;
  }
  int tid = threadIdx.x;
#pragma unroll
  for(int j=0;j<16;j++) red[tid][j]=s[j];
  __syncthreads();
  for(int off=128; off>0; off>>=1){
    if(tid<off){
#pragma unroll
      for(int j=0;j<16;j++) red[tid][j]+=red[tid+off][j];
    }
    __syncthreads();
  }
  if(tid<16) atomicAdd(relmean+tid, red[0][tid]*(1.0f/(float)E));
}

// ---- CSR build over REAL edges only (self-loops handled analytically) ----
__global__ void k_count(const int* __restrict__ edges, int* __restrict__ counts, int E, int N){
  int e = blockIdx.x*blockDim.x + threadIdx.x;
  if(e>=E) return;
  int d = edges[E+e];
  if(d<0) d=0; if(d>=N) d=N-1;
  atomicAdd(counts+d, 1);
}

__global__ void k_scan(const int* __restrict__ counts, int* __restrict__ rowstart,
                       int* __restrict__ cursor, int N){
  __shared__ int part[1024];
  int tid = threadIdx.x;
  int chunk = (N + 1023) >> 10;
  int lo = tid*chunk, hi = lo+chunk; if(hi>N) hi=N; if(lo>N) lo=N;
  int s=0;
  for(int i=lo;i<hi;i++) s += counts[i];
  part[tid]=s;
  __syncthreads();
  for(int off=1; off<1024; off<<=1){
    int v = (tid>=off) ? part[tid-off] : 0;
    __syncthreads();
    part[tid] += v;
    __syncthreads();
  }
  int run = (tid==0) ? 0 : part[tid-1];
  for(int i=lo;i<hi;i++){ rowstart[i]=run; cursor[i]=run; run += counts[i]; }
  if(tid==1023) rowstart[N] = part[1023];
}

// scatter src AND the rel row (packed bf16, CSR order) so the hot loop reads
// rel sequentially with no eid indirection.
__global__ void k_scatter(const int* __restrict__ edges, const float* __restrict__ relation,
                          int* __restrict__ cursor,
                          int* __restrict__ adj_src, u32* __restrict__ rel_s, int E, int N){
  int e = blockIdx.x*blockDim.x + threadIdx.x;
  if(e>=E) return;
  int s = edges[e], d = edges[E+e];
  if(d<0) d=0; if(d>=N) d=N-1;
  int pos = atomicAdd(cursor+d, 1);
  adj_src[pos]=s;
  const float4* rp = (const float4*)(relation + (size_t)e*16);
  float4 q0=rp[0], q1=rp[1], q2=rp[2], q3=rp[3];
  uint4* dst = (uint4*)(rel_s + (size_t)pos*8);
  dst[0] = make_uint4(pk2(q0.x,q0.y), pk2(q0.z,q0.w), pk2(q1.x,q1.y), pk2(q1.z,q1.w));
  dst[1] = make_uint4(pk2(q2.x,q2.y), pk2(q2.z,q2.w), pk2(q3.x,q3.y), pk2(q3.z,q3.w));
}

// ---- embedding + input projection: h[N][64] (f32) ----
__global__ void k_embed(const float* __restrict__ nodes,
                        const float* __restrict__ time_emb, const float* __restrict__ type_emb,
                        const float* __restrict__ biway_emb, const float* __restrict__ islink_emb,
                        const float* __restrict__ projw, const float* __restrict__ projb,
                        float* __restrict__ h, int N){
  __shared__ float W[64][65];
  __shared__ float h0[4][64];
  int tid = threadIdx.x;
  for(int i=tid; i<64*64; i+=256) W[i>>6][i&63] = projw[i];
  __syncthreads();
  int wave = tid>>6, lane = tid&63;
  int node = blockIdx.x*4 + wave;
  if(node<N){
    const float* nr = nodes + (size_t)node*20;
    float v; int c = lane;
    if(c<16){
      int t=(int)nr[0]; t = t<0?0:(t>287?287:t);
      v = time_emb[t*16+c];
    } else if(c<32){
      int ty=(int)nr[1]; ty = ty<0?0:(ty>15?15:ty);
      v = type_emb[ty*16+(c-16)];
    } else if(c<40){
      int bw=(int)nr[2]; bw = bw<0?0:(bw>1?1:bw);
      v = biway_emb[bw*8+(c-32)];
    } else if(c<48){
      int il=(int)nr[3]; il = il<0?0:(il>1?1:il);
      v = islink_emb[il*8+(c-40)];
    } else {
      v = nr[4 + (c-48)];
    }
    h0[wave][lane]=v;
  }
  __syncthreads();
  if(node<N){
    float acc = projb[lane];
#pragma unroll
    for(int k=0;k<64;k++) acc += W[lane][k]*h0[wave][k];
    h[(size_t)node*64+lane]=acc;
  }
}

// ---- xl/xr = h @ {wl,wr}.T + {bl,br}, stored bf16. 16 nodes/block ----
__global__ void k_xlr(const float* __restrict__ h,
                      const float* __restrict__ wl, const float* __restrict__ bl,
                      const float* __restrict__ wr, const float* __restrict__ br,
                      u16* __restrict__ xl, u16* __restrict__ xr, int N){
  __shared__ float hs[NT*64];
  int tid = threadIdx.x;
  int base = blockIdx.x*NT;
  int nvalid = N - base; if(nvalid > NT) nvalid = NT;
  if(nvalid == NT){
    *(float4*)(hs + tid*4) = *(const float4*)(h + (size_t)base*64 + tid*4);
  } else {
    for(int i=tid; i<NT*64; i+=256) hs[i] = (i < nvalid*64) ? h[(size_t)base*64+i] : 0.f;
  }
  __syncthreads();
  int o = tid;   // output channel 0..255
  const float4* wl4 = (const float4*)(wl + (size_t)o*64);
  const float4* wr4 = (const float4*)(wr + (size_t)o*64);
  float blv = bl[o], brv = br[o];
  float accl[NT], accr[NT];
#pragma unroll
  for(int n=0;n<NT;n++){ accl[n]=blv; accr[n]=brv; }
  for(int kk=0; kk<16; kk++){
    float4 a = wl4[kk];
    float4 b = wr4[kk];
#pragma unroll
    for(int n=0;n<NT;n++){
      float4 hv = *(const float4*)(hs + n*64 + kk*4);
      accl[n] += a.x*hv.x + a.y*hv.y + a.z*hv.z + a.w*hv.w;
      accr[n] += b.x*hv.x + b.y*hv.y + b.z*hv.z + b.w*hv.w;
    }
  }
  for(int n=0;n<nvalid;n++){
    xl[(size_t)(base+n)*HHID + o] = f2bf(accl[n]);
    xr[(size_t)(base+n)*HHID + o] = f2bf(accr[n]);
  }
}

// ---- fused per-node: edge logits + online softmax + aggregation + residual ----
// CSR holds real in-edges only; the self-loop uses the per-wave constant
// ep_sl = we @ relmean and initializes the online softmax. rel comes from the
// CSR-ordered bf16 rel_s (sequential broadcast reads, no eid indirection).
__global__ void __launch_bounds__(256, 4)
k_fused(const int* __restrict__ rowstart, const int* __restrict__ adj_src,
        const u32* __restrict__ rel_s, const float* __restrict__ relmean,
        const float* __restrict__ we, const float* __restrict__ att,
        const u16* __restrict__ xl, const u16* __restrict__ xr,
        const float* __restrict__ gat_b,
        float* __restrict__ h, int N, float* __restrict__ outp){
  const int lane = threadIdx.x & 63;
  const int sub = lane & 15;
  const int wid = (blockIdx.x*blockDim.x + threadIdx.x) >> 6;
  const int nw  = (gridDim.x*blockDim.x) >> 6;

  // per-wave constants: packed we rows (32 regs), att quad, ep_sl quad
  u32 wpk[32];
  {
    const float4* wp = (const float4*)(we + (size_t)lane*64);
#pragma unroll
    for(int i=0;i<16;i++){
      float4 t = wp[i];
      wpk[i*2+0] = pk2(t.x, t.y);
      wpk[i*2+1] = pk2(t.z, t.w);
    }
  }
  const float4 at4 = *(const float4*)(att + lane*4);
  float es0=0.f, es1=0.f, es2=0.f, es3=0.f;
  {
    float rm[16];
    const float4* mp = (const float4*)relmean;
    float4 m0=mp[0], m1=mp[1], m2=mp[2], m3=mp[3];
    rm[0]=m0.x; rm[1]=m0.y; rm[2]=m0.z; rm[3]=m0.w;
    rm[4]=m1.x; rm[5]=m1.y; rm[6]=m1.z; rm[7]=m1.w;
    rm[8]=m2.x; rm[9]=m2.y; rm[10]=m2.z; rm[11]=m2.w;
    rm[12]=m3.x; rm[13]=m3.y; rm[14]=m3.z; rm[15]=m3.w;
#pragma unroll
    for(int kk=0;kk<8;kk++){
      es0 += rm[2*kk]*bflo(wpk[0*8+kk]) + rm[2*kk+1]*bfhi(wpk[0*8+kk]);
      es1 += rm[2*kk]*bflo(wpk[1*8+kk]) + rm[2*kk+1]*bfhi(wpk[1*8+kk]);
      es2 += rm[2*kk]*bflo(wpk[2*8+kk]) + rm[2*kk+1]*bfhi(wpk[2*8+kk]);
      es3 += rm[2*kk]*bflo(wpk[3*8+kk]) + rm[2*kk+1]*bfhi(wpk[3*8+kk]);
    }
  }

  for(int node = wid; node < N; node += nw){
    const int lo = rowstart[node], hi = rowstart[node+1];
    uint2 pb = *(const uint2*)(xr + (size_t)node*HHID + lane*4);
    float bv0=bflo(pb.x), bv1=bfhi(pb.x), bv2=bflo(pb.y), bv3=bfhi(pb.y);

    // self-loop first: av = xl[node], ep = ep_sl; initializes online softmax
    float m, den, a0, a1, a2, a3;
    {
      uint2 ps = *(const uint2*)(xl + (size_t)node*HHID + lane*4);
      float sv0=bflo(ps.x), sv1=bfhi(ps.x), sv2=bflo(ps.y), sv3=bfhi(ps.y);
      float c = 0.f;
#pragma unroll
      for(int j=0;j<4;j++){
        float epj = (j==0)?es0:(j==1)?es1:(j==2)?es2:es3;
        float avj = (j==0)?sv0:(j==1)?sv1:(j==2)?sv2:sv3;
        float bvj = (j==0)?bv0:(j==1)?bv1:(j==2)?bv2:bv3;
        float mm = avj + bvj + epj;
        mm = (mm>0.f) ? mm : 0.2f*mm;
        float atj = (j==0)?at4.x:(j==1)?at4.y:(j==2)?at4.z:at4.w;
        c += mm*atj;
      }
      c += __shfl_xor(c, 1);
      c += __shfl_xor(c, 2);
      c += __shfl_xor(c, 4);
      c += __shfl_xor(c, 8);
      m = c; den = 1.f;
      a0 = sv0; a1 = sv1; a2 = sv2; a3 = sv3;
    }

    // real in-edges
    int sv0i = 0;
    if(lo < hi) sv0i = adj_src[lo];
    for(int p=lo; p<hi; p++){
      int sv1i = 0;
      if(p+1 < hi) sv1i = adj_src[p+1];
      int sv = sv0i; if(sv<0) sv=0; if(sv>=N) sv=N-1;

      // rel row: sequential 32B broadcast
      const uint4* rp = (const uint4*)(rel_s + (size_t)p*8);
      uint4 rq0 = rp[0], rq1 = rp[1];
      float rc[16];
      rc[0]=bflo(rq0.x); rc[1]=bfhi(rq0.x); rc[2]=bflo(rq0.y); rc[3]=bfhi(rq0.y);
      rc[4]=bflo(rq0.z); rc[5]=bfhi(rq0.z); rc[6]=bflo(rq0.w); rc[7]=bfhi(rq0.w);
      rc[8]=bflo(rq1.x); rc[9]=bfhi(rq1.x); rc[10]=bflo(rq1.y); rc[11]=bfhi(rq1.y);
      rc[12]=bflo(rq1.z); rc[13]=bfhi(rq1.z); rc[14]=bflo(rq1.w); rc[15]=bfhi(rq1.w);

      uint2 pa = *(const uint2*)(xl + (size_t)sv*HHID + lane*4);
      float av0=bflo(pa.x), av1=bfhi(pa.x), av2=bflo(pa.y), av3=bfhi(pa.y);

      float c = 0.f;
#pragma unroll
      for(int j=0;j<4;j++){
        float ep = 0.f;
#pragma unroll
        for(int kk=0;kk<8;kk++){
          u32 w = wpk[j*8+kk];
          ep += rc[2*kk]*bflo(w) + rc[2*kk+1]*bfhi(w);
        }
        float avj = (j==0)?av0:(j==1)?av1:(j==2)?av2:av3;
        float bvj = (j==0)?bv0:(j==1)?bv1:(j==2)?bv2:bv3;
        float mm = avj + bvj + ep;
        mm = (mm>0.f) ? mm : 0.2f*mm;
        float atj = (j==0)?at4.x:(j==1)?at4.y:(j==2)?at4.z:at4.w;
        c += mm*atj;
      }
      c += __shfl_xor(c, 1);
      c += __shfl_xor(c, 2);
      c += __shfl_xor(c, 4);
      c += __shfl_xor(c, 8);

      if(c > m){
        float sc = __expf(m - c);
        den *= sc; a0 *= sc; a1 *= sc; a2 *= sc; a3 *= sc;
        m = c;
      }
      float wgt = __expf(c - m);
      den += wgt;
      a0 += wgt*av0; a1 += wgt*av1; a2 += wgt*av2; a3 += wgt*av3;

      sv0i = sv1i;
    }

    float inv = 1.0f/den;
    float v0=a0*inv, v1=a1*inv, v2=a2*inv, v3=a3*inv;
    v0 += __shfl_xor(v0,16); v0 += __shfl_xor(v0,32);
    v1 += __shfl_xor(v1,16); v1 += __shfl_xor(v1,32);
    v2 += __shfl_xor(v2,16); v2 += __shfl_xor(v2,32);
    v3 += __shfl_xor(v3,16); v3 += __shfl_xor(v3,32);
    if(lane < 16){
      int cb = sub*4;
      float4 hv = *(const float4*)(h + (size_t)node*64 + cb);
      const float4 gb = *(const float4*)(gat_b + cb);
      float o0 = fmaxf(0.25f*v0 + gb.x + hv.x, 0.f);
      float o1 = fmaxf(0.25f*v1 + gb.y + hv.y, 0.f);
      float o2 = fmaxf(0.25f*v2 + gb.z + hv.z, 0.f);
      float o3 = fmaxf(0.25f*v3 + gb.w + hv.w, 0.f);
      *(float4*)(h + (size_t)node*64 + cb) = make_float4(o0,o1,o2,o3);
      if(outp) *(float4*)(outp + (size_t)node*64 + cb) = make_float4(o0,o1,o2,o3);
    }
  }
}

extern "C" void kernel_launch(void* const* d_in, const int* in_sizes, int n_in,
                              void* d_out, int out_size, void* d_ws, size_t ws_size,
                              hipStream_t stream) {
  const float* nodes     = (const float*)d_in[0];
  const int*   edges     = (const int*)d_in[1];
  const float* relation  = (const float*)d_in[2];
  const float* time_emb  = (const float*)d_in[3];
  const float* type_emb  = (const float*)d_in[4];
  const float* biway_emb = (const float*)d_in[5];
  const float* islink_emb= (const float*)d_in[6];
  const float* proj_w    = (const float*)d_in[7];
  const float* proj_b    = (const float*)d_in[8];
  const float* lin_l_w   = (const float*)d_in[9];
  const float* lin_l_b   = (const float*)d_in[10];
  const float* lin_r_w   = (const float*)d_in[11];
  const float* lin_r_b   = (const float*)d_in[12];
  const float* lin_e_w   = (const float*)d_in[13];
  const float* att       = (const float*)d_in[14];
  const float* gat_b     = (const float*)d_in[15];

  const int N  = in_sizes[0] / 20;
  const int E  = in_sizes[1] / 2;

  size_t off = 0;
  auto alloc = [&](size_t bytes)->size_t {
    size_t p = off;
    off += ((bytes + 255) / 256) * 256;
    return p;
  };
  size_t o_h        = alloc((size_t)N*64*4);        // f32
  size_t o_xl       = alloc((size_t)N*HHID*2);      // bf16
  size_t o_xr       = alloc((size_t)N*HHID*2);      // bf16
  size_t o_rels     = alloc((size_t)E*32);          // bf16 rel rows, CSR order
  size_t o_relmean  = alloc(64*4);
  size_t o_counts   = alloc((size_t)N*4);
  size_t o_rowstart = alloc((size_t)(N+1)*4);
  size_t o_cursor   = alloc((size_t)(N+1)*4);
  size_t o_adjsrc   = alloc((size_t)E*4);

  if (off > ws_size) {
    TopoAggregator_33217277067466_kernel<<<2048, 256, 0, stream>>>(
        (float*)d_out, out_size, 100.0f);   // marker ~100: ws too small
    return;
  }

  char* w = (char*)d_ws;
  float* h        = (float*)(w + o_h);
  u16*   xl       = (u16*)(w + o_xl);
  u16*   xr       = (u16*)(w + o_xr);
  u32*   rel_s    = (u32*)(w + o_rels);
  float* relmean  = (float*)(w + o_relmean);
  int*   counts   = (int*)(w + o_counts);
  int*   rowstart = (int*)(w + o_rowstart);
  int*   cursor   = (int*)(w + o_cursor);
  int*   adj_src  = (int*)(w + o_adjsrc);

  k_zero<<<(N+255)/256, 256, 0, stream>>>(counts, relmean, N);
  k_relmean<<<64, 256, 0, stream>>>(relation, relmean, E);
  k_count<<<(E+255)/256, 256, 0, stream>>>(edges, counts, E, N);
  k_scan<<<1, 1024, 0, stream>>>(counts, rowstart, cursor, N);
  k_scatter<<<(E+255)/256, 256, 0, stream>>>(edges, relation, cursor, adj_src, rel_s, E, N);

  k_embed<<<(N+3)/4, 256, 0, stream>>>(nodes, time_emb, type_emb, biway_emb, islink_emb,
                                       proj_w, proj_b, h, N);

  for(int l=0; l<2; l++){
    k_xlr<<<(N+NT-1)/NT, 256, 0, stream>>>(h,
        lin_l_w + (size_t)l*HHID*64, lin_l_b + (size_t)l*HHID,
        lin_r_w + (size_t)l*HHID*64, lin_r_b + (size_t)l*HHID,
        xl, xr, N);
    k_fused<<<4096, 256, 0, stream>>>(rowstart, adj_src, rel_s, relmean,
        lin_e_w + (size_t)l*HHID*16, att + (size_t)l*HEADS*64,
        xl, xr, gat_b + (size_t)l*64,
        h, N,
        (l==1) ? (float*)d_out : (float*)nullptr);
  }
  k_marker<<<1, 64, 0, stream>>>(rowstart, h, (float*)d_out, N, E);
}

// Round 14
// 867.336 us; speedup vs baseline: 1.9943x; 1.2491x over previous
//
#include <hip/hip_runtime.h>

typedef unsigned short u16;
typedef unsigned int u32;

__device__ __forceinline__ float bf2f(u16 u){ union{u32 i; float f;} v; v.i=((u32)u)<<16; return v.f; }
__device__ __forceinline__ float bflo(u32 p){ union{u32 i; float f;} v; v.i=p<<16; return v.f; }
__device__ __forceinline__ float bfhi(u32 p){ union{u32 i; float f;} v; v.i=p&0xffff0000u; return v.f; }
__device__ __forceinline__ u16 f2bf(float x){ union{float f; u32 i;} v; v.f=x; u32 b=v.i;
  return (u16)((b + 0x7fffu + ((b>>16)&1u))>>16); }
__device__ __forceinline__ u32 pk2(float a, float b){ return ((u32)f2bf(b)<<16) | (u32)f2bf(a); }

#define HEADS 4
#define HHID 256   // HEADS*HID
#define NT 16      // nodes per block in k_xlr

// ---- fill d_out with a float value (diagnostic only) ----
__global__ void TopoAggregator_33217277067466_kernel(float* __restrict__ out, int n, float val){
  for(int i = blockIdx.x*blockDim.x + threadIdx.x; i < n; i += gridDim.x*blockDim.x)
    out[i] = val;
}

// ---- post-hoc invariant marker: touches d_out ONLY on failure ----
// codes: 400 CSR broken, 500 h all-zero
__global__ void k_marker(const int* __restrict__ rowstart, const float* __restrict__ h,
                         float* __restrict__ out, int N, int E){
  if(threadIdx.x!=0 || blockIdx.x!=0) return;
  float M = 0.f;
  if(rowstart[N] != E) M = 400.f;
  else {
    int allz = 1;
    for(int i=0;i<128;i++) if(h[i]!=0.f){ allz=0; break; }
    if(allz) M = 500.f;
  }
  if(M != 0.f) out[0] = M;
}

// ---- zero counts[N] and relmean[16] ----
__global__ void k_zero(int* __restrict__ counts, float* __restrict__ relmean, int N){
  int i = blockIdx.x*blockDim.x + threadIdx.x;
  if(i < N) counts[i] = 0;
  if(i < 16) relmean[i] = 0.f;
}

// ---- relation mean over E rows of 16 (f32) ----
__global__ void k_relmean(const float* __restrict__ rel, float* __restrict__ relmean, int E){
  __shared__ float red[256][16];
  float s[16];
#pragma unroll
  for(int j=0;j<16;j++) s[j]=0.f;
  for(int r = blockIdx.x*blockDim.x + threadIdx.x; r < E; r += gridDim.x*blockDim.x){
    const float4* p = (const float4*)(rel + (size_t)r*16);
    float4 a=p[0], b=p[1], c=p[2], d=p[3];
    s[0]+=a.x; s[1]+=a.y; s[2]+=a.z; s[3]+=a.w;
    s[4]+=b.x; s[5]+=b.y; s[6]+=b.z; s[7]+=b.w;
    s[8]+=c.x; s[9]+=c.y; s[10]+=c.z; s[11]+=c.w;
    s[12]+=d.x; s[13]+=d.y; s[14]+=d.z; s[15]+=d.w;
  }
  int tid = threadIdx.x;
#pragma unroll
  for(int j=0;j<16;j++) red[tid][j]=s[j];
  __syncthreads();
  for(int off=128; off>0; off>>=1){
    if(tid<off){
#pragma unroll
      for(int j=0;j<16;j++) red[tid][j]+=red[tid+off][j];
    }
    __syncthreads();
  }
  if(tid<16) atomicAdd(relmean+tid, red[0][tid]*(1.0f/(float)E));
}

// ---- CSR build over REAL edges only (self-loops handled analytically) ----
__global__ void k_count(const int* __restrict__ edges, int* __restrict__ counts, int E, int N){
  int e = blockIdx.x*blockDim.x + threadIdx.x;
  if(e>=E) return;
  int d = edges[E+e];
  if(d<0) d=0; if(d>=N) d=N-1;
  atomicAdd(counts+d, 1);
}

// ---- 3-phase parallel exclusive scan over counts[N] ----
#define STILE 1024
__global__ void k_scan_a(const int* __restrict__ counts, int* __restrict__ tilesum, int N){
  __shared__ int red[256];
  int base = blockIdx.x*STILE;
  int tid = threadIdx.x;
  int s = 0;
  for(int i=tid; i<STILE; i+=256){
    int idx = base + i;
    s += (idx < N) ? counts[idx] : 0;
  }
  red[tid] = s;
  __syncthreads();
  for(int off=128; off>0; off>>=1){
    if(tid<off) red[tid] += red[tid+off];
    __syncthreads();
  }
  if(tid==0) tilesum[blockIdx.x] = red[0];
}

__global__ void k_scan_b(const int* __restrict__ tilesum, int* __restrict__ tileoff, int nT){
  __shared__ int buf[1024];
  int tid = threadIdx.x;
  buf[tid] = (tid < nT) ? tilesum[tid] : 0;
  __syncthreads();
  for(int off=1; off<1024; off<<=1){
    int v = (tid>=off) ? buf[tid-off] : 0;
    __syncthreads();
    buf[tid] += v;
    __syncthreads();
  }
  if(tid < nT) tileoff[tid] = (tid==0) ? 0 : buf[tid-1];
}

__global__ void k_scan_c(const int* __restrict__ counts, const int* __restrict__ tileoff,
                         int* __restrict__ rowstart, int* __restrict__ cursor, int N){
  __shared__ int buf[STILE];
  int base = blockIdx.x*STILE;
  int tid = threadIdx.x;
  int idx = base + tid;
  int c = (idx < N) ? counts[idx] : 0;
  buf[tid] = c;
  __syncthreads();
  for(int off=1; off<1024; off<<=1){
    int v = (tid>=off) ? buf[tid-off] : 0;
    __syncthreads();
    buf[tid] += v;
    __syncthreads();
  }
  int excl = buf[tid] - c + tileoff[blockIdx.x];
  if(idx < N){ rowstart[idx]=excl; cursor[idx]=excl; }
  if(idx == N-1) rowstart[N] = excl + c;
}

// scatter src AND the rel row (packed bf16, CSR order) so the hot loop reads
// rel sequentially with no eid indirection.
__global__ void k_scatter(const int* __restrict__ edges, const float* __restrict__ relation,
                          int* __restrict__ cursor,
                          int* __restrict__ adj_src, u32* __restrict__ rel_s, int E, int N){
  int e = blockIdx.x*blockDim.x + threadIdx.x;
  if(e>=E) return;
  int s = edges[e], d = edges[E+e];
  if(d<0) d=0; if(d>=N) d=N-1;
  int pos = atomicAdd(cursor+d, 1);
  adj_src[pos]=s;
  const float4* rp = (const float4*)(relation + (size_t)e*16);
  float4 q0=rp[0], q1=rp[1], q2=rp[2], q3=rp[3];
  uint4* dst = (uint4*)(rel_s + (size_t)pos*8);
  dst[0] = make_uint4(pk2(q0.x,q0.y), pk2(q0.z,q0.w), pk2(q1.x,q1.y), pk2(q1.z,q1.w));
  dst[1] = make_uint4(pk2(q2.x,q2.y), pk2(q2.z,q2.w), pk2(q3.x,q3.y), pk2(q3.z,q3.w));
}

// ---- embedding + input projection: h[N][64] (f32) ----
__global__ void k_embed(const float* __restrict__ nodes,
                        const float* __restrict__ time_emb, const float* __restrict__ type_emb,
                        const float* __restrict__ biway_emb, const float* __restrict__ islink_emb,
                        const float* __restrict__ projw, const float* __restrict__ projb,
                        float* __restrict__ h, int N){
  __shared__ float W[64][65];
  __shared__ float h0[4][64];
  int tid = threadIdx.x;
  for(int i=tid; i<64*64; i+=256) W[i>>6][i&63] = projw[i];
  __syncthreads();
  int wave = tid>>6, lane = tid&63;
  int node = blockIdx.x*4 + wave;
  if(node<N){
    const float* nr = nodes + (size_t)node*20;
    float v; int c = lane;
    if(c<16){
      int t=(int)nr[0]; t = t<0?0:(t>287?287:t);
      v = time_emb[t*16+c];
    } else if(c<32){
      int ty=(int)nr[1]; ty = ty<0?0:(ty>15?15:ty);
      v = type_emb[ty*16+(c-16)];
    } else if(c<40){
      int bw=(int)nr[2]; bw = bw<0?0:(bw>1?1:bw);
      v = biway_emb[bw*8+(c-32)];
    } else if(c<48){
      int il=(int)nr[3]; il = il<0?0:(il>1?1:il);
      v = islink_emb[il*8+(c-40)];
    } else {
      v = nr[4 + (c-48)];
    }
    h0[wave][lane]=v;
  }
  __syncthreads();
  if(node<N){
    float acc = projb[lane];
#pragma unroll
    for(int k=0;k<64;k++) acc += W[lane][k]*h0[wave][k];
    h[(size_t)node*64+lane]=acc;
  }
}

// ---- xl/xr = h @ {wl,wr}.T + {bl,br}, stored bf16. 16 nodes/block ----
__global__ void k_xlr(const float* __restrict__ h,
                      const float* __restrict__ wl, const float* __restrict__ bl,
                      const float* __restrict__ wr, const float* __restrict__ br,
                      u16* __restrict__ xl, u16* __restrict__ xr, int N){
  __shared__ float hs[NT*64];
  int tid = threadIdx.x;
  int base = blockIdx.x*NT;
  int nvalid = N - base; if(nvalid > NT) nvalid = NT;
  if(nvalid == NT){
    *(float4*)(hs + tid*4) = *(const float4*)(h + (size_t)base*64 + tid*4);
  } else {
    for(int i=tid; i<NT*64; i+=256) hs[i] = (i < nvalid*64) ? h[(size_t)base*64+i] : 0.f;
  }
  __syncthreads();
  int o = tid;   // output channel 0..255
  const float4* wl4 = (const float4*)(wl + (size_t)o*64);
  const float4* wr4 = (const float4*)(wr + (size_t)o*64);
  float blv = bl[o], brv = br[o];
  float accl[NT], accr[NT];
#pragma unroll
  for(int n=0;n<NT;n++){ accl[n]=blv; accr[n]=brv; }
  for(int kk=0; kk<16; kk++){
    float4 a = wl4[kk];
    float4 b = wr4[kk];
#pragma unroll
    for(int n=0;n<NT;n++){
      float4 hv = *(const float4*)(hs + n*64 + kk*4);
      accl[n] += a.x*hv.x + a.y*hv.y + a.z*hv.z + a.w*hv.w;
      accr[n] += b.x*hv.x + b.y*hv.y + b.z*hv.z + b.w*hv.w;
    }
  }
  for(int n=0;n<nvalid;n++){
    xl[(size_t)(base+n)*HHID + o] = f2bf(accl[n]);
    xr[(size_t)(base+n)*HHID + o] = f2bf(accr[n]);
  }
}

// ---- fused per-node: edge logits + online softmax + aggregation + residual ----
__global__ void __launch_bounds__(256, 4)
k_fused(const int* __restrict__ rowstart, const int* __restrict__ adj_src,
        const u32* __restrict__ rel_s, const float* __restrict__ relmean,
        const float* __restrict__ we, const float* __restrict__ att,
        const u16* __restrict__ xl, const u16* __restrict__ xr,
        const float* __restrict__ gat_b,
        float* __restrict__ h, int N, float* __restrict__ outp){
  const int lane = threadIdx.x & 63;
  const int sub = lane & 15;
  const int wid = (blockIdx.x*blockDim.x + threadIdx.x) >> 6;
  const int nw  = (gridDim.x*blockDim.x) >> 6;

  // per-wave constants: packed we rows (32 regs), att quad, ep_sl quad
  u32 wpk[32];
  {
    const float4* wp = (const float4*)(we + (size_t)lane*64);
#pragma unroll
    for(int i=0;i<16;i++){
      float4 t = wp[i];
      wpk[i*2+0] = pk2(t.x, t.y);
      wpk[i*2+1] = pk2(t.z, t.w);
    }
  }
  const float4 at4 = *(const float4*)(att + lane*4);
  float es0=0.f, es1=0.f, es2=0.f, es3=0.f;
  {
    float rm[16];
    const float4* mp = (const float4*)relmean;
    float4 m0=mp[0], m1=mp[1], m2=mp[2], m3=mp[3];
    rm[0]=m0.x; rm[1]=m0.y; rm[2]=m0.z; rm[3]=m0.w;
    rm[4]=m1.x; rm[5]=m1.y; rm[6]=m1.z; rm[7]=m1.w;
    rm[8]=m2.x; rm[9]=m2.y; rm[10]=m2.z; rm[11]=m2.w;
    rm[12]=m3.x; rm[13]=m3.y; rm[14]=m3.z; rm[15]=m3.w;
#pragma unroll
    for(int kk=0;kk<8;kk++){
      es0 += rm[2*kk]*bflo(wpk[0*8+kk]) + rm[2*kk+1]*bfhi(wpk[0*8+kk]);
      es1 += rm[2*kk]*bflo(wpk[1*8+kk]) + rm[2*kk+1]*bfhi(wpk[1*8+kk]);
      es2 += rm[2*kk]*bflo(wpk[2*8+kk]) + rm[2*kk+1]*bfhi(wpk[2*8+kk]);
      es3 += rm[2*kk]*bflo(wpk[3*8+kk]) + rm[2*kk+1]*bfhi(wpk[3*8+kk]);
    }
  }

  for(int node = wid; node < N; node += nw){
    const int lo = rowstart[node], hi = rowstart[node+1];
    uint2 pb = *(const uint2*)(xr + (size_t)node*HHID + lane*4);
    float bv0=bflo(pb.x), bv1=bfhi(pb.x), bv2=bflo(pb.y), bv3=bfhi(pb.y);

    // self-loop first: av = xl[node], ep = ep_sl; initializes online softmax
    float m, den, a0, a1, a2, a3;
    {
      uint2 ps = *(const uint2*)(xl + (size_t)node*HHID + lane*4);
      float sv0=bflo(ps.x), sv1=bfhi(ps.x), sv2=bflo(ps.y), sv3=bfhi(ps.y);
      float c = 0.f;
#pragma unroll
      for(int j=0;j<4;j++){
        float epj = (j==0)?es0:(j==1)?es1:(j==2)?es2:es3;
        float avj = (j==0)?sv0:(j==1)?sv1:(j==2)?sv2:sv3;
        float bvj = (j==0)?bv0:(j==1)?bv1:(j==2)?bv2:bv3;
        float mm = avj + bvj + epj;
        mm = (mm>0.f) ? mm : 0.2f*mm;
        float atj = (j==0)?at4.x:(j==1)?at4.y:(j==2)?at4.z:at4.w;
        c += mm*atj;
      }
      c += __shfl_xor(c, 1);
      c += __shfl_xor(c, 2);
      c += __shfl_xor(c, 4);
      c += __shfl_xor(c, 8);
      m = c; den = 1.f;
      a0 = sv0; a1 = sv1; a2 = sv2; a3 = sv3;
    }

    // real in-edges
    int sv0i = 0;
    if(lo < hi) sv0i = adj_src[lo];
    for(int p=lo; p<hi; p++){
      int sv1i = 0;
      if(p+1 < hi) sv1i = adj_src[p+1];
      int sv = sv0i; if(sv<0) sv=0; if(sv>=N) sv=N-1;

      // rel row: sequential 32B broadcast
      const uint4* rp = (const uint4*)(rel_s + (size_t)p*8);
      uint4 rq0 = rp[0], rq1 = rp[1];
      float rc[16];
      rc[0]=bflo(rq0.x); rc[1]=bfhi(rq0.x); rc[2]=bflo(rq0.y); rc[3]=bfhi(rq0.y);
      rc[4]=bflo(rq0.z); rc[5]=bfhi(rq0.z); rc[6]=bflo(rq0.w); rc[7]=bfhi(rq0.w);
      rc[8]=bflo(rq1.x); rc[9]=bfhi(rq1.x); rc[10]=bflo(rq1.y); rc[11]=bfhi(rq1.y);
      rc[12]=bflo(rq1.z); rc[13]=bfhi(rq1.z); rc[14]=bflo(rq1.w); rc[15]=bfhi(rq1.w);

      uint2 pa = *(const uint2*)(xl + (size_t)sv*HHID + lane*4);
      float av0=bflo(pa.x), av1=bfhi(pa.x), av2=bflo(pa.y), av3=bfhi(pa.y);

      float c = 0.f;
#pragma unroll
      for(int j=0;j<4;j++){
        float ep = 0.f;
#pragma unroll
        for(int kk=0;kk<8;kk++){
          u32 w = wpk[j*8+kk];
          ep += rc[2*kk]*bflo(w) + rc[2*kk+1]*bfhi(w);
        }
        float avj = (j==0)?av0:(j==1)?av1:(j==2)?av2:av3;
        float bvj = (j==0)?bv0:(j==1)?bv1:(j==2)?bv2:bv3;
        float mm = avj + bvj + ep;
        mm = (mm>0.f) ? mm : 0.2f*mm;
        float atj = (j==0)?at4.x:(j==1)?at4.y:(j==2)?at4.z:at4.w;
        c += mm*atj;
      }
      c += __shfl_xor(c, 1);
      c += __shfl_xor(c, 2);
      c += __shfl_xor(c, 4);
      c += __shfl_xor(c, 8);

      if(c > m){
        float sc = __expf(m - c);
        den *= sc; a0 *= sc; a1 *= sc; a2 *= sc; a3 *= sc;
        m = c;
      }
      float wgt = __expf(c - m);
      den += wgt;
      a0 += wgt*av0; a1 += wgt*av1; a2 += wgt*av2; a3 += wgt*av3;

      sv0i = sv1i;
    }

    float inv = 1.0f/den;
    float v0=a0*inv, v1=a1*inv, v2=a2*inv, v3=a3*inv;
    v0 += __shfl_xor(v0,16); v0 += __shfl_xor(v0,32);
    v1 += __shfl_xor(v1,16); v1 += __shfl_xor(v1,32);
    v2 += __shfl_xor(v2,16); v2 += __shfl_xor(v2,32);
    v3 += __shfl_xor(v3,16); v3 += __shfl_xor(v3,32);
    if(lane < 16){
      int cb = sub*4;
      float4 hv = *(const float4*)(h + (size_t)node*64 + cb);
      const float4 gb = *(const float4*)(gat_b + cb);
      float o0 = fmaxf(0.25f*v0 + gb.x + hv.x, 0.f);
      float o1 = fmaxf(0.25f*v1 + gb.y + hv.y, 0.f);
      float o2 = fmaxf(0.25f*v2 + gb.z + hv.z, 0.f);
      float o3 = fmaxf(0.25f*v3 + gb.w + hv.w, 0.f);
      *(float4*)(h + (size_t)node*64 + cb) = make_float4(o0,o1,o2,o3);
      if(outp) *(float4*)(outp + (size_t)node*64 + cb) = make_float4(o0,o1,o2,o3);
    }
  }
}

extern "C" void kernel_launch(void* const* d_in, const int* in_sizes, int n_in,
                              void* d_out, int out_size, void* d_ws, size_t ws_size,
                              hipStream_t stream) {
  const float* nodes     = (const float*)d_in[0];
  const int*   edges     = (const int*)d_in[1];
  const float* relation  = (const float*)d_in[2];
  const float* time_emb  = (const float*)d_in[3];
  const float* type_emb  = (const float*)d_in[4];
  const float* biway_emb = (const float*)d_in[5];
  const float* islink_emb= (const float*)d_in[6];
  const float* proj_w    = (const float*)d_in[7];
  const float* proj_b    = (const float*)d_in[8];
  const float* lin_l_w   = (const float*)d_in[9];
  const float* lin_l_b   = (const float*)d_in[10];
  const float* lin_r_w   = (const float*)d_in[11];
  const float* lin_r_b   = (const float*)d_in[12];
  const float* lin_e_w   = (const float*)d_in[13];
  const float* att       = (const float*)d_in[14];
  const float* gat_b     = (const float*)d_in[15];

  const int N  = in_sizes[0] / 20;
  const int E  = in_sizes[1] / 2;
  const int nT = (N + STILE - 1) / STILE;

  size_t off = 0;
  auto alloc = [&](size_t bytes)->size_t {
    size_t p = off;
    off += ((bytes + 255) / 256) * 256;
    return p;
  };
  size_t o_h        = alloc((size_t)N*64*4);        // f32
  size_t o_xl       = alloc((size_t)N*HHID*2);      // bf16
  size_t o_xr       = alloc((size_t)N*HHID*2);      // bf16
  size_t o_rels     = alloc((size_t)E*32);          // bf16 rel rows, CSR order
  size_t o_relmean  = alloc(64*4);
  size_t o_counts   = alloc((size_t)N*4);
  size_t o_rowstart = alloc((size_t)(N+1)*4);
  size_t o_cursor   = alloc((size_t)(N+1)*4);
  size_t o_adjsrc   = alloc((size_t)E*4);
  size_t o_tilesum  = alloc((size_t)nT*4);
  size_t o_tileoff  = alloc((size_t)nT*4);

  if (off > ws_size) {
    TopoAggregator_33217277067466_kernel<<<2048, 256, 0, stream>>>(
        (float*)d_out, out_size, 100.0f);   // marker ~100: ws too small
    return;
  }

  char* w = (char*)d_ws;
  float* h        = (float*)(w + o_h);
  u16*   xl       = (u16*)(w + o_xl);
  u16*   xr       = (u16*)(w + o_xr);
  u32*   rel_s    = (u32*)(w + o_rels);
  float* relmean  = (float*)(w + o_relmean);
  int*   counts   = (int*)(w + o_counts);
  int*   rowstart = (int*)(w + o_rowstart);
  int*   cursor   = (int*)(w + o_cursor);
  int*   adj_src  = (int*)(w + o_adjsrc);
  int*   tilesum  = (int*)(w + o_tilesum);
  int*   tileoff  = (int*)(w + o_tileoff);

  k_zero<<<(N+255)/256, 256, 0, stream>>>(counts, relmean, N);
  k_relmean<<<64, 256, 0, stream>>>(relation, relmean, E);
  k_count<<<(E+255)/256, 256, 0, stream>>>(edges, counts, E, N);
  k_scan_a<<<nT, 256, 0, stream>>>(counts, tilesum, N);
  k_scan_b<<<1, 1024, 0, stream>>>(tilesum, tileoff, nT);
  k_scan_c<<<nT, 1024, 0, stream>>>(counts, tileoff, rowstart, cursor, N);
  k_scatter<<<(E+255)/256, 256, 0, stream>>>(edges, relation, cursor, adj_src, rel_s, E, N);

  k_embed<<<(N+3)/4, 256, 0, stream>>>(nodes, time_emb, type_emb, biway_emb, islink_emb,
                                       proj_w, proj_b, h, N);

  for(int l=0; l<2; l++){
    k_xlr<<<(N+NT-1)/NT, 256, 0, stream>>>(h,
        lin_l_w + (size_t)l*HHID*64, lin_l_b + (size_t)l*HHID,
        lin_r_w + (size_t)l*HHID*64, lin_r_b + (size_t)l*HHID,
        xl, xr, N);
    k_fused<<<4096, 256, 0, stream>>>(rowstart, adj_src, rel_s, relmean,
        lin_e_w + (size_t)l*HHID*16, att + (size_t)l*HEADS*64,
        xl, xr, gat_b + (size_t)l*64,
        h, N,
        (l==1) ? (float*)d_out : (float*)nullptr);
  }
  k_marker<<<1, 64, 0, stream>>>(rowstart, h, (float*)d_out, N, E);
}